// Round 11
// baseline (651.121 us; speedup 1.0000x reference)
//
#include <hip/hip_runtime.h>
#include <hip/hip_bf16.h>

// Problem constants (from reference)
constexpr int N_ = 6144;      // nodes
constexpr int E_ = 196608;    // edges per graph
constexpr int F_ = 256;       // feature dim (== H)
constexpr int D_ = 512;       // fusion dim
constexpr int G_ = 4;         // graphs
constexpr int A_ = 128;       // attention bottleneck

constexpr int CHUNK = 4096;                     // f4 per chunk (80B traffic each -> 327KB)
constexpr long U_F4 = (long)N_ * N_ / 4;        // 9437184 = 2304 * 4096
constexpr int NCHUNKS = (int)(U_F4 / CHUNK);    // 2304

typedef short bf16x8 __attribute__((ext_vector_type(8)));
typedef float f32x4 __attribute__((ext_vector_type(4)));
typedef float f4 __attribute__((ext_vector_type(4)));
typedef int i4 __attribute__((ext_vector_type(4)));
typedef __hip_bfloat16 hb;

__device__ inline float b2f(unsigned short u) {
    union { unsigned u32; float f; } x; x.u32 = ((unsigned)u) << 16; return x.f;
}
__device__ inline unsigned short f2bu(float f) {
    hb b = __float2bfloat16(f);
    return *reinterpret_cast<unsigned short*>(&b);
}

#define GLD_LDS16(gp, lp) \
    __builtin_amdgcn_global_load_lds((const __attribute__((address_space(1))) void*)(gp), \
                                     (__attribute__((address_space(3))) void*)(lp), 16, 0, 0)

// ---------------------------------------------------------------------------
// Streaming (fusion): o0 = w0*Cc + w1*Cs ; o3 = Cc ; o4 = Cs.
// PER-KERNEL work stealing: each kernel owns chunk range [cbeg,cend) and its
// own cursor. Stream-seed blocks steal from t=0; compute blocks join after
// their tile. Chunk = 4096 f4, inner loop guard-free ILP-4 (32 VGPR).
// ---------------------------------------------------------------------------
struct SP {
    const f4* Cc; const f4* Cs; const float* fw;
    f4* o0; f4* o3; f4* o4;
    int* cursor;          // this kernel's chunk counter (starts at 0)
    int cbeg; int cend;   // chunk id range owned by this kernel
};

__device__ void stream_steal(const SP sp)
{
    __shared__ int s_c;
    float fa = sp.fw[0], fb = sp.fw[1];
    float mx = fmaxf(fa, fb);
    float ea = expf(fa - mx), eb = expf(fb - mx);
    float w0 = ea / (ea + eb), w1 = eb / (ea + eb);
    const long S = blockDim.x;
    while (true) {
        __syncthreads();
        if (threadIdx.x == 0) s_c = atomicAdd(sp.cursor, 1);
        __syncthreads();
        int c = sp.cbeg + s_c;
        if (c >= sp.cend) return;
        const long base = (long)c * CHUNK;
        const long end  = base + CHUNK;
        // CHUNK divisible by 4*S for S=256 and S=1024 -> no guards
        for (long i = base + threadIdx.x; i < end; i += 4 * S) {
            f4 a0 = __builtin_nontemporal_load(sp.Cc + i);
            f4 b0 = __builtin_nontemporal_load(sp.Cs + i);
            f4 a1 = __builtin_nontemporal_load(sp.Cc + i + S);
            f4 b1 = __builtin_nontemporal_load(sp.Cs + i + S);
            f4 a2 = __builtin_nontemporal_load(sp.Cc + i + 2 * S);
            f4 b2 = __builtin_nontemporal_load(sp.Cs + i + 2 * S);
            f4 a3 = __builtin_nontemporal_load(sp.Cc + i + 3 * S);
            f4 b3 = __builtin_nontemporal_load(sp.Cs + i + 3 * S);
            __builtin_nontemporal_store(a0, sp.o3 + i);
            __builtin_nontemporal_store(b0, sp.o4 + i);
            __builtin_nontemporal_store(w0 * a0 + w1 * b0, sp.o0 + i);
            __builtin_nontemporal_store(a1, sp.o3 + i + S);
            __builtin_nontemporal_store(b1, sp.o4 + i + S);
            __builtin_nontemporal_store(w0 * a1 + w1 * b1, sp.o0 + i + S);
            __builtin_nontemporal_store(a2, sp.o3 + i + 2 * S);
            __builtin_nontemporal_store(b2, sp.o4 + i + 2 * S);
            __builtin_nontemporal_store(w0 * a2 + w1 * b2, sp.o0 + i + 2 * S);
            __builtin_nontemporal_store(a3, sp.o3 + i + 3 * S);
            __builtin_nontemporal_store(b3, sp.o4 + i + 3 * S);
            __builtin_nontemporal_store(w0 * a3 + w1 * b3, sp.o0 + i + 3 * S);
        }
    }
}

__global__ void k_drain(SP sp) { stream_steal(sp); }

// ---------------------------------------------------------------------------
// Prologue: out1 = copy(x_content); all fp32->bf16 conversions; zero curs.
// Blocks [0,nsb) steal; blocks [nsb, nsb+PB) do compute then steal.
// ---------------------------------------------------------------------------
__global__ void k_prep(const float* __restrict__ xc, f4* __restrict__ o1,
                       const float* __restrict__ xs, ushort4* __restrict__ xsb,
                       const float* __restrict__ Wl, ushort4* __restrict__ Wlb,
                       const float* __restrict__ Wr, ushort4* __restrict__ Wrb,
                       const float* __restrict__ lin, ushort4* __restrict__ linb,
                       const float* __restrict__ aw, ushort4* __restrict__ awb,
                       const float* __restrict__ rw, ushort4* __restrict__ rwb,
                       i4* __restrict__ cursz, int PB, SP sp)
{
    if ((int)blockIdx.x >= sp.cbeg - sp.cbeg + 0 && (int)blockIdx.x < 0) {}  // (no-op)
    if ((int)blockIdx.x >= PB) { stream_steal(sp); return; }
    const int cb = blockIdx.x;
    const long nz = (long)G_ * N_ / 4;          // curs zero (int4)
    const long n0 = (long)N_ * F_ / 4;
    const long n1 = (long)G_ * N_ * F_ / 4;
    const long n2 = (long)G_ * 3 * F_ * F_ / 4;
    const long n4 = (long)G_ * D_ * F_ / 4;
    const long n5 = (long)A_ * D_ / 4;
    const long n6 = (long)D_ * D_ / 4;
    const long T = nz + n0 + n1 + 2 * n2 + n4 + n5 + n6;
    long stride = (long)PB * blockDim.x;
    for (long u = (long)cb * blockDim.x + threadIdx.x; u < T; u += stride) {
        long v = u;
        if (v < nz) { cursz[v] = i4{0, 0, 0, 0}; continue; }
        v -= nz;
        if (v < n0) {
            f4 x = __builtin_nontemporal_load((const f4*)xc + v);
            __builtin_nontemporal_store(x, o1 + v);
            continue;
        }
        v -= n0;
        const float* s; ushort4* d;
        if (v < n1) { s = xs; d = xsb; }
        else {
            v -= n1;
            if (v < n2) { s = Wl; d = Wlb; }
            else {
                v -= n2;
                if (v < n2) { s = Wr; d = Wrb; }
                else {
                    v -= n2;
                    if (v < n4) { s = lin; d = linb; }
                    else {
                        v -= n4;
                        if (v < n5) { s = aw; d = awb; }
                        else { v -= n5; s = rw; d = rwb; }
                    }
                }
            }
        }
        f4 x = *((const f4*)s + v);
        ushort4 o;
        o.x = f2bu(x[0]); o.y = f2bu(x[1]); o.z = f2bu(x[2]); o.w = f2bu(x[3]);
        d[v] = o;
    }
    stream_steal(sp);
}

// ---------------------------------------------------------------------------
// CSR build: count -> scan -> fill (compute blocks join the steal pool)
// NOTE: compute blocks come AFTER the nsb stream-seed blocks in the grid.
// ---------------------------------------------------------------------------
__global__ void k_count(const int* __restrict__ ei, int* __restrict__ cnt,
                        int nsb, SP sp)
{
    if ((int)blockIdx.x >= nsb) {
        long i = (long)(blockIdx.x - nsb) * blockDim.x + threadIdx.x;
        int g = (int)(i / E_);
        int e = (int)(i % E_);
        int dst = ei[(long)g * 2 * E_ + E_ + e];
        atomicAdd(&cnt[g * N_ + dst], 1);
    }
    stream_steal(sp);
}

__global__ void k_scan(int* __restrict__ cnt_cursor, int* __restrict__ row_ptr,
                       float* __restrict__ deg, int nsb, SP sp)
{
    if ((int)blockIdx.x >= nsb) {
        int g = blockIdx.x - nsb;
        __shared__ int sdata[1024];
        __shared__ int s_off;
        if (threadIdx.x == 0) s_off = 0;
        __syncthreads();
        for (int base = 0; base < N_; base += 1024) {
            int idx = g * N_ + base + threadIdx.x;
            int v = cnt_cursor[idx];
            sdata[threadIdx.x] = v;
            __syncthreads();
            for (int d = 1; d < 1024; d <<= 1) {
                int t = (threadIdx.x >= d) ? sdata[threadIdx.x - d] : 0;
                __syncthreads();
                sdata[threadIdx.x] += t;
                __syncthreads();
            }
            int incl = sdata[threadIdx.x];
            int excl = incl - v;
            int rp = s_off + excl;
            row_ptr[g * (N_ + 1) + base + threadIdx.x] = rp;
            cnt_cursor[idx] = rp;
            deg[idx] = (float)(v > 1 ? v : 1);
            __syncthreads();
            if (threadIdx.x == 1023) s_off += incl;
            __syncthreads();
        }
        if (threadIdx.x == 0) row_ptr[g * (N_ + 1) + N_] = s_off;
    }
    stream_steal(sp);
}

__global__ void k_fill(const int* __restrict__ ei, int* __restrict__ cursor,
                       int* __restrict__ csr_src, int nsb, SP sp)
{
    if ((int)blockIdx.x >= nsb) {
        long i = (long)(blockIdx.x - nsb) * blockDim.x + threadIdx.x;
        int g = (int)(i / E_);
        int e = (int)(i % E_);
        int src = ei[(long)g * 2 * E_ + e];
        int dst = ei[(long)g * 2 * E_ + E_ + e];
        int pos = atomicAdd(&cursor[g * N_ + dst], 1);
        csr_src[(long)g * E_ + pos] = src;
    }
    stream_steal(sp);
}

// ---------------------------------------------------------------------------
// Mean aggregation, XCD-pinned: graph g -> XCDs {2g,2g+1} via bid%8.
// One wave per node; 4 edges/iter (quarter-wave, 32B/lane). Steal after.
// ---------------------------------------------------------------------------
__global__ __launch_bounds__(256) void k_aggregate(
    const hb* __restrict__ x, const int* __restrict__ csr_src,
    const int* __restrict__ row_ptr, const float* __restrict__ deg,
    hb* __restrict__ m, int nsb, SP sp)
{
    if ((int)blockIdx.x >= nsb) {
        int b = blockIdx.x - nsb;
        int g = (b & 7) >> 1;
        int idx = ((b >> 3) << 1) | (b & 1);       // 0..N/4-1 within graph
        int node = idx * 4 + (threadIdx.x >> 6);
        int lane = threadIdx.x & 63;
        int qq = lane >> 4;
        int l16 = (lane & 15) * 16;
        const hb* xg = x + (long)g * N_ * F_;
        const int* rp = row_ptr + g * (N_ + 1);
        const int* cs = csr_src + (long)g * E_;
        int s = __builtin_amdgcn_readfirstlane(rp[node]);
        int e = __builtin_amdgcn_readfirstlane(rp[node + 1]);
        float a[16] = {};
        #pragma unroll 2
        for (int j = s; j < e; j += 4) {
            if (j + qq < e) {
                int src = cs[j + qq];
                const bf16x8* p = (const bf16x8*)(xg + (long)src * F_ + l16);
                bf16x8 v0 = p[0], v1 = p[1];
                #pragma unroll
                for (int q = 0; q < 8; ++q) a[q]     += b2f((unsigned short)v0[q]);
                #pragma unroll
                for (int q = 0; q < 8; ++q) a[q + 8] += b2f((unsigned short)v1[q]);
            }
        }
        #pragma unroll
        for (int q = 0; q < 16; ++q) {
            a[q] += __shfl_xor(a[q], 16);
            a[q] += __shfl_xor(a[q], 32);
        }
        if (qq == 0) {
            float inv = 1.0f / deg[g * N_ + node];
            bf16x8 lo, hi;
            #pragma unroll
            for (int q = 0; q < 8; ++q) { lo[q] = (short)f2bu(a[q] * inv); hi[q] = (short)f2bu(a[q + 8] * inv); }
            *(bf16x8*)(m + ((long)g * N_ + node) * F_ + l16) = lo;
            *(bf16x8*)(m + ((long)g * N_ + node) * F_ + l16 + 8) = hi;
        }
    }
    stream_steal(sp);
}

// ---------------------------------------------------------------------------
// bf16 MFMA NT GEMM, 1-D grid (stream seeds first), optional XCD pin,
// optional fused epilogues. 128x128 tile, 256 thr, BK=64, fp32 accum.
// LOGITS: relu(h)·W2 + b2 -> logits.  FUSEOUT: out2 = relu(resid + sum_g w_g feats_g).
// Every compute block joins the steal pool after its tile.
// ---------------------------------------------------------------------------
template <bool DUAL, bool RELU, bool LOGITS, bool FUSEOUT, bool PIN>
__global__ __launch_bounds__(256) void k_mfma_nt(
    const hb* __restrict__ A1, const hb* __restrict__ B1,
    const hb* __restrict__ A2, const hb* __restrict__ B2,
    const float* __restrict__ bias, hb* __restrict__ C,
    int ncols, int nrows, int ng, int Nc, int K,
    long a_batch, long b_batch, long bias_batch, long c_batch,
    const float* __restrict__ W2, const float* __restrict__ b2,
    float* __restrict__ logits,
    const float* __restrict__ lgAll, const hb* __restrict__ fAll,
    float* __restrict__ o2,
    int nsb, SP sp)
{
    if ((int)blockIdx.x >= nsb) {
    int b = blockIdx.x - nsb;
    int g, col, row;
    if (PIN) {
        g = (b & 7) >> 1;
        int idx = ((b >> 3) << 1) | (b & 1);
        col = idx % ncols; row = idx / ncols;
    } else {
        col = b % ncols;
        int r2 = b / ncols;
        row = r2 % nrows; g = r2 / nrows;
    }
    const int row0 = row * 128;
    const int col0 = col * 128;

    const hb* A1p = A1 + (long)g * a_batch;
    const hb* B1p = B1 + (long)g * b_batch;
    const hb* A2p = nullptr;
    const hb* B2p = nullptr;
    if (DUAL) { A2p = A2 + (long)g * a_batch; B2p = B2 + (long)g * b_batch; }
    const float* biasp = bias + (long)g * bias_batch;
    hb* Cp = C + (long)g * c_batch;

    __shared__ hb As[128 * 64];
    __shared__ hb Bs[128 * 64];
    __shared__ float sLog[2][128];
    __shared__ float sW[128][4];

    const int tid = threadIdx.x;
    const int lane = tid & 63;
    const int wid = tid >> 6;
    const int wr = wid >> 1;
    const int wc = wid & 1;

    if (FUSEOUT) {
        if (tid < 128) {
            int rr = row0 + tid;
            float l0 = lgAll[rr], l1 = lgAll[N_ + rr], l2 = lgAll[2 * N_ + rr], l3 = lgAll[3 * N_ + rr];
            float mx = fmaxf(fmaxf(l0, l1), fmaxf(l2, l3));
            float e0 = expf(l0 - mx), e1 = expf(l1 - mx), e2 = expf(l2 - mx), e3 = expf(l3 - mx);
            float inv = 1.f / (e0 + e1 + e2 + e3);
            sW[tid][0] = e0 * inv; sW[tid][1] = e1 * inv;
            sW[tid][2] = e2 * inv; sW[tid][3] = e3 * inv;
        }
    }

    const int srow = tid >> 3;
    const int sk8  = (tid & 7) * 8;

    f32x4 acc[4][4] = {};

    const int fr  = lane & 15;
    const int fkq = (lane >> 4) * 8;

    const int npass = DUAL ? 2 : 1;
    for (int pass = 0; pass < npass; ++pass) {
        const hb* A = (DUAL && pass) ? A2p : A1p;
        const hb* B = (DUAL && pass) ? B2p : B1p;
        for (int k0 = 0; k0 < K; k0 += 64) {
            __syncthreads();
            #pragma unroll
            for (int c = 0; c < 4; ++c) {
                int r = c * 32 + srow;
                GLD_LDS16(A + (long)(row0 + r) * K + k0 + sk8, As + r * 64 + sk8);
                GLD_LDS16(B + (long)(col0 + r) * K + k0 + sk8, Bs + r * 64 + sk8);
            }
            __syncthreads();

            bf16x8 af[4][2], bfr[4][2];
            #pragma unroll
            for (int m = 0; m < 4; ++m)
                #pragma unroll
                for (int kk = 0; kk < 2; ++kk)
                    af[m][kk] = *(const bf16x8*)(As + (wr * 64 + m * 16 + fr) * 64 + kk * 32 + fkq);
            #pragma unroll
            for (int n = 0; n < 4; ++n)
                #pragma unroll
                for (int kk = 0; kk < 2; ++kk)
                    bfr[n][kk] = *(const bf16x8*)(Bs + (wc * 64 + n * 16 + fr) * 64 + kk * 32 + fkq);

            #pragma unroll
            for (int m = 0; m < 4; ++m)
                #pragma unroll
                for (int n = 0; n < 4; ++n)
                    #pragma unroll
                    for (int kk = 0; kk < 2; ++kk)
                        acc[m][n] = __builtin_amdgcn_mfma_f32_16x16x32_bf16(
                            af[m][kk], bfr[n][kk], acc[m][n], 0, 0, 0);
        }
    }

    const int r4 = (lane >> 4) * 4;
    const int cc = lane & 15;

    if (LOGITS) {
        float w2v[4], bv[4];
        #pragma unroll
        for (int n = 0; n < 4; ++n) {
            int c2 = wc * 64 + n * 16 + cc;
            w2v[n] = W2[c2];
            bv[n]  = biasp[c2];
        }
        #pragma unroll
        for (int m = 0; m < 4; ++m) {
            #pragma unroll
            for (int j = 0; j < 4; ++j) {
                float p = 0.f;
                #pragma unroll
                for (int n = 0; n < 4; ++n) {
                    float h = fmaxf(acc[m][n][j] + bv[n], 0.f);
                    p += h * w2v[n];
                }
                p += __shfl_xor(p, 1); p += __shfl_xor(p, 2);
                p += __shfl_xor(p, 4); p += __shfl_xor(p, 8);
                if (cc == 0) sLog[wc][wr * 64 + m * 16 + r4 + j] = p;
            }
        }
        __syncthreads();
        if (tid < 128)
            logits[(long)g * N_ + row0 + tid] = sLog[0][tid] + sLog[1][tid] + b2[0];
    } else if (FUSEOUT) {
        const unsigned short* fu = (const unsigned short*)fAll;
        #pragma unroll
        for (int m = 0; m < 4; ++m) {
            #pragma unroll
            for (int n = 0; n < 4; ++n) {
                int c2 = col0 + wc * 64 + n * 16 + cc;
                float bv = biasp[c2];
                #pragma unroll
                for (int j = 0; j < 4; ++j) {
                    int rl = wr * 64 + m * 16 + r4 + j;
                    int rr = row0 + rl;
                    float s = acc[m][n][j] + bv;
                    #pragma unroll
                    for (int gg = 0; gg < 4; ++gg)
                        s += sW[rl][gg] * b2f(fu[((long)gg * N_ + rr) * D_ + c2]);
                    __builtin_nontemporal_store(fmaxf(s, 0.f), o2 + (long)rr * D_ + c2);
                }
            }
        }
    } else {
        #pragma unroll
        for (int m = 0; m < 4; ++m) {
            #pragma unroll
            for (int n = 0; n < 4; ++n) {
                int c2 = col0 + wc * 64 + n * 16 + cc;
                float bv = biasp[c2];
                #pragma unroll
                for (int j = 0; j < 4; ++j) {
                    int rr = row0 + wr * 64 + m * 16 + r4 + j;
                    float v = acc[m][n][j] + bv;
                    if (RELU) v = fmaxf(v, 0.f);
                    Cp[(long)rr * Nc + c2] = __float2bfloat16(v);
                }
            }
        }
    }
    }
    stream_steal(sp);
}

// ---------------------------------------------------------------------------
extern "C" void kernel_launch(void* const* d_in, const int* in_sizes, int n_in,
                              void* d_out, int out_size, void* d_ws, size_t ws_size,
                              hipStream_t stream)
{
    const float* xs        = (const float*)d_in[0];
    const int*   ei        = (const int*)  d_in[1];
    const float* x_content = (const float*)d_in[2];
    const float* sage_Wl   = (const float*)d_in[3];
    const float* sage_bl   = (const float*)d_in[4];
    const float* sage_Wr   = (const float*)d_in[5];
    const float* lin_W     = (const float*)d_in[6];
    const float* lin_b     = (const float*)d_in[7];
    const float* att_W1    = (const float*)d_in[8];
    const float* att_b1    = (const float*)d_in[9];
    const float* att_W2    = (const float*)d_in[10];
    const float* att_b2    = (const float*)d_in[11];
    const float* res_W     = (const float*)d_in[12];
    const float* res_b     = (const float*)d_in[13];
    const float* fusion_w  = (const float*)d_in[14];
    const float* Cc        = (const float*)d_in[15];
    const float* Cs        = (const float*)d_in[16];

    float* out0 = (float*)d_out;                    // fusion_expression [N,N]
    float* out1 = out0 + (size_t)N_ * N_;           // x_content [N,F]
    float* out2 = out1 + (size_t)N_ * F_;           // structure_features [N,D]
    float* out3 = out2 + (size_t)N_ * D_;           // C_content [N,N]
    float* out4 = out3 + (size_t)N_ * N_;           // C_structure [N,N]

    char* w = (char*)d_ws;
    auto alloc = [&](size_t bytes) {
        char* p = w;
        w += (bytes + 255) & ~(size_t)255;
        return p;
    };
    hb* xsb   = (hb*)alloc((size_t)G_ * N_ * F_ * 2);
    hb* xA    = (hb*)alloc((size_t)G_ * N_ * F_ * 2);
    hb* xB    = (hb*)alloc((size_t)G_ * N_ * F_ * 2);
    hb* mb    = (hb*)alloc((size_t)G_ * N_ * F_ * 2);
    hb* feats = (hb*)alloc((size_t)G_ * N_ * D_ * 2);
    hb* Wlb   = (hb*)alloc((size_t)G_ * 3 * F_ * F_ * 2);
    hb* Wrb   = (hb*)alloc((size_t)G_ * 3 * F_ * F_ * 2);
    hb* linWb = (hb*)alloc((size_t)G_ * D_ * F_ * 2);
    hb* attWb = (hb*)alloc((size_t)A_ * D_ * 2);
    hb* resWb = (hb*)alloc((size_t)D_ * D_ * 2);
    float* logit = (float*)alloc((size_t)G_ * N_ * 4);
    float* deg   = (float*)alloc((size_t)G_ * N_ * 4);
    int*   rowp  = (int*)  alloc((size_t)G_ * (N_ + 1) * 4);
    int*   curs  = (int*)  alloc((size_t)G_ * N_ * 4);
    int*   csrc  = (int*)  alloc((size_t)G_ * E_ * 4);
    int*   scur  = (int*)  alloc(256);               // 14 per-kernel steal cursors

    // chunk budget per kernel (sums to 2304)
    // order: prep count scan fill agg0 sage0 agg1 sage1 agg2 sage2 feats att resid drain
    const int chunks[14] = {256, 96, 32, 96, 160, 128, 160, 128, 160, 128, 128, 256, 320, 256};
    int cb[15];
    cb[0] = 0;
    for (int i = 0; i < 14; ++i) cb[i + 1] = cb[i] + chunks[i];
    auto mkSP = [&](int i) {
        SP sp;
        sp.Cc = (const f4*)Cc; sp.Cs = (const f4*)Cs; sp.fw = fusion_w;
        sp.o0 = (f4*)out0; sp.o3 = (f4*)out3; sp.o4 = (f4*)out4;
        sp.cursor = scur + i; sp.cbeg = cb[i]; sp.cend = cb[i + 1];
        return sp;
    };

    const int PREPB = 1024;   // prep compute blocks
    const int SEED_P = 512;   // stream-seed blocks
    const int SEED   = 256;
    const int SEED_S = 64;

    // 0) zero all steal cursors (one tiny memset, captured in graph)
    hipMemsetAsync(scur, 0, 64, stream);

    // 1) prologue: out1 copy + all bf16 conversions + curs zero (+ steal)
    k_prep<<<PREPB + SEED_P, 256, 0, stream>>>(
        x_content, (f4*)out1, xs, (ushort4*)xsb,
        sage_Wl, (ushort4*)Wlb, sage_Wr, (ushort4*)Wrb,
        lin_W, (ushort4*)linWb, att_W1, (ushort4*)attWb, res_W, (ushort4*)resWb,
        (i4*)curs, PREPB, mkSP(0));

    // 2) CSR build (seed blocks first, compute blocks join pool after)
    k_count<<<SEED + G_ * E_ / 256, 256, 0, stream>>>(ei, curs, SEED, mkSP(1));
    k_scan<<<SEED_S + G_, 1024, 0, stream>>>(curs, rowp, deg, SEED_S, mkSP(2));
    k_fill<<<SEED + G_ * E_ / 256, 256, 0, stream>>>(ei, curs, csrc, SEED, mkSP(3));

    // 3) GNN: 3 layers, ping-pong xsb -> xA -> xB -> xA (XCD-pinned)
    const hb* xin = xsb;
    hb* xout = xA;
    for (int layer = 0; layer < 3; ++layer) {
        k_aggregate<<<SEED + G_ * N_ / 4, 256, 0, stream>>>(
            xin, csrc, rowp, deg, mb, SEED, mkSP(4 + 2 * layer));
        k_mfma_nt<true, true, false, false, true>
            <<<SEED + (F_ / 128) * (N_ / 128) * G_, 256, 0, stream>>>(
            mb, Wlb + (size_t)layer * F_ * F_,
            xin, Wrb + (size_t)layer * F_ * F_,
            sage_bl + (size_t)layer * F_, xout,
            F_ / 128, N_ / 128, G_, F_, F_,
            (long)N_ * F_, (long)3 * F_ * F_, (long)3 * F_, (long)N_ * F_,
            nullptr, nullptr, nullptr, nullptr, nullptr, nullptr,
            SEED, mkSP(5 + 2 * layer));
        xin = xout;
        xout = (layer == 0) ? xB : xA;
    }
    const hb* xg = xA;  // after layer 2 result lands in xA

    // 4) feats = xg @ lin_W^T + lin_b   [G,N,D] bf16  (pinned)
    k_mfma_nt<false, false, false, false, true>
        <<<SEED + (D_ / 128) * (N_ / 128) * G_, 256, 0, stream>>>(
        xg, linWb, nullptr, nullptr, lin_b, feats,
        D_ / 128, N_ / 128, G_, D_, F_,
        (long)N_ * F_, (long)D_ * F_, (long)D_, (long)N_ * D_,
        nullptr, nullptr, nullptr, nullptr, nullptr, nullptr,
        SEED, mkSP(10));

    // 5) logits = relu(feats @ att_W1^T + att_b1) . W2 + b2  (pinned, fused)
    k_mfma_nt<false, true, true, false, true>
        <<<SEED_P + (A_ / 128) * (N_ / 128) * G_, 256, 0, stream>>>(
        feats, attWb, nullptr, nullptr, att_b1, nullptr,
        A_ / 128, N_ / 128, G_, A_, D_,
        (long)N_ * D_, 0L, 0L, 0L,
        att_W2, att_b2, logit, nullptr, nullptr, nullptr,
        SEED_P, mkSP(11));

    // 6) out2 = relu(feats[0] @ res_W^T + res_b + sum_g w_g feats_g)
    k_mfma_nt<false, false, false, true, false>
        <<<SEED_P + (D_ / 128) * (N_ / 128) * 1, 256, 0, stream>>>(
        feats, resWb, nullptr, nullptr, res_b, nullptr,
        D_ / 128, N_ / 128, 1, D_, D_,
        0L, 0L, 0L, 0L,
        nullptr, nullptr, nullptr, logit, feats, out2,
        SEED_P, mkSP(12));

    // 7) drain the final chunk range at full grid
    k_drain<<<1024, 256, 0, stream>>>(mkSP(13));
}

// Round 12
// 422.888 us; speedup vs baseline: 1.5397x; 1.5397x over previous
//
#include <hip/hip_runtime.h>
#include <hip/hip_bf16.h>

// Problem constants (from reference)
constexpr int N_ = 6144;      // nodes
constexpr int E_ = 196608;    // edges per graph
constexpr int F_ = 256;       // feature dim (== H)
constexpr int D_ = 512;       // fusion dim
constexpr int G_ = 4;         // graphs
constexpr int A_ = 128;       // attention bottleneck

typedef short bf16x8 __attribute__((ext_vector_type(8)));
typedef float f32x4 __attribute__((ext_vector_type(4)));
typedef float f4 __attribute__((ext_vector_type(4)));
typedef int i4 __attribute__((ext_vector_type(4)));
typedef __hip_bfloat16 hb;

__device__ inline float b2f(unsigned short u) {
    union { unsigned u32; float f; } x; x.u32 = ((unsigned)u) << 16; return x.f;
}
__device__ inline unsigned short f2bu(float f) {
    hb b = __float2bfloat16(f);
    return *reinterpret_cast<unsigned short*>(&b);
}

#define GLD_LDS16(gp, lp) \
    __builtin_amdgcn_global_load_lds((const __attribute__((address_space(1))) void*)(gp), \
                                     (__attribute__((address_space(3))) void*)(lp), 16, 0, 0)

// ---------------------------------------------------------------------------
// Streaming side-work (fusion): o0 = w0*Cc + w1*Cs ; o3 = Cc ; o4 = Cs.
// Disjoint [ib,ie) slices over N*N/4 f4s, hosted by the FIRST nsb blocks of
// each hybrid kernel (resident from t=0). ILP-4 grid-stride (r9 verbatim —
// best measured variant; ILP-8 and work-stealing both regressed).
// ---------------------------------------------------------------------------
struct SP {
    const f4* Cc; const f4* Cs; const float* fw;
    f4* o0; f4* o3; f4* o4;
    long ib; long ie; int nsb;
};

__device__ void stream_slice(const SP sp, int sb)
{
    float fa = sp.fw[0], fb = sp.fw[1];
    float mx = fmaxf(fa, fb);
    float ea = expf(fa - mx), eb = expf(fb - mx);
    float w0 = ea / (ea + eb), w1 = eb / (ea + eb);
    const long S = (long)sp.nsb * blockDim.x;
    long i = sp.ib + (long)sb * blockDim.x + threadIdx.x;
    for (; i + 3 * S < sp.ie; i += 4 * S) {
        f4 a0 = __builtin_nontemporal_load(sp.Cc + i);
        f4 b0 = __builtin_nontemporal_load(sp.Cs + i);
        f4 a1 = __builtin_nontemporal_load(sp.Cc + i + S);
        f4 b1 = __builtin_nontemporal_load(sp.Cs + i + S);
        f4 a2 = __builtin_nontemporal_load(sp.Cc + i + 2 * S);
        f4 b2 = __builtin_nontemporal_load(sp.Cs + i + 2 * S);
        f4 a3 = __builtin_nontemporal_load(sp.Cc + i + 3 * S);
        f4 b3 = __builtin_nontemporal_load(sp.Cs + i + 3 * S);
        __builtin_nontemporal_store(a0, sp.o3 + i);
        __builtin_nontemporal_store(b0, sp.o4 + i);
        __builtin_nontemporal_store(w0 * a0 + w1 * b0, sp.o0 + i);
        __builtin_nontemporal_store(a1, sp.o3 + i + S);
        __builtin_nontemporal_store(b1, sp.o4 + i + S);
        __builtin_nontemporal_store(w0 * a1 + w1 * b1, sp.o0 + i + S);
        __builtin_nontemporal_store(a2, sp.o3 + i + 2 * S);
        __builtin_nontemporal_store(b2, sp.o4 + i + 2 * S);
        __builtin_nontemporal_store(w0 * a2 + w1 * b2, sp.o0 + i + 2 * S);
        __builtin_nontemporal_store(a3, sp.o3 + i + 3 * S);
        __builtin_nontemporal_store(b3, sp.o4 + i + 3 * S);
        __builtin_nontemporal_store(w0 * a3 + w1 * b3, sp.o0 + i + 3 * S);
    }
    for (; i < sp.ie; i += S) {
        f4 a = __builtin_nontemporal_load(sp.Cc + i);
        f4 b = __builtin_nontemporal_load(sp.Cs + i);
        __builtin_nontemporal_store(a, sp.o3 + i);
        __builtin_nontemporal_store(b, sp.o4 + i);
        __builtin_nontemporal_store(w0 * a + w1 * b, sp.o0 + i);
    }
}

__global__ void k_tail(SP sp) { stream_slice(sp, blockIdx.x); }

// ---------------------------------------------------------------------------
// Prologue: out1 = copy(x_content); all fp32->bf16 conversions; zero curs.
// Blocks [0,nsb) stream; blocks [nsb, nsb+PB) do compute (grid-stride).
// ---------------------------------------------------------------------------
__global__ void k_prep(const float* __restrict__ xc, f4* __restrict__ o1,
                       const float* __restrict__ xs, ushort4* __restrict__ xsb,
                       const float* __restrict__ Wl, ushort4* __restrict__ Wlb,
                       const float* __restrict__ Wr, ushort4* __restrict__ Wrb,
                       const float* __restrict__ lin, ushort4* __restrict__ linb,
                       const float* __restrict__ aw, ushort4* __restrict__ awb,
                       const float* __restrict__ rw, ushort4* __restrict__ rwb,
                       i4* __restrict__ cursz, int PB, SP sp)
{
    if ((int)blockIdx.x < sp.nsb) { stream_slice(sp, blockIdx.x); return; }
    const int cb = blockIdx.x - sp.nsb;
    const long nz = (long)G_ * N_ / 4;          // curs zero (int4)
    const long n0 = (long)N_ * F_ / 4;
    const long n1 = (long)G_ * N_ * F_ / 4;
    const long n2 = (long)G_ * 3 * F_ * F_ / 4;
    const long n4 = (long)G_ * D_ * F_ / 4;
    const long n5 = (long)A_ * D_ / 4;
    const long n6 = (long)D_ * D_ / 4;
    const long T = nz + n0 + n1 + 2 * n2 + n4 + n5 + n6;
    long stride = (long)PB * blockDim.x;
    for (long u = (long)cb * blockDim.x + threadIdx.x; u < T; u += stride) {
        long v = u;
        if (v < nz) { cursz[v] = i4{0, 0, 0, 0}; continue; }
        v -= nz;
        if (v < n0) {
            f4 x = __builtin_nontemporal_load((const f4*)xc + v);
            __builtin_nontemporal_store(x, o1 + v);
            continue;
        }
        v -= n0;
        const float* s; ushort4* d;
        if (v < n1) { s = xs; d = xsb; }
        else {
            v -= n1;
            if (v < n2) { s = Wl; d = Wlb; }
            else {
                v -= n2;
                if (v < n2) { s = Wr; d = Wrb; }
                else {
                    v -= n2;
                    if (v < n4) { s = lin; d = linb; }
                    else {
                        v -= n4;
                        if (v < n5) { s = aw; d = awb; }
                        else { v -= n5; s = rw; d = rwb; }
                    }
                }
            }
        }
        f4 x = *((const f4*)s + v);
        ushort4 o;
        o.x = f2bu(x[0]); o.y = f2bu(x[1]); o.z = f2bu(x[2]); o.w = f2bu(x[3]);
        d[v] = o;
    }
}

// ---------------------------------------------------------------------------
// CSR build: count -> scan -> fill (stream blocks first in each grid)
// ---------------------------------------------------------------------------
__global__ void k_count(const int* __restrict__ ei, int* __restrict__ cnt, SP sp)
{
    if ((int)blockIdx.x < sp.nsb) { stream_slice(sp, blockIdx.x); return; }
    long i = (long)(blockIdx.x - sp.nsb) * blockDim.x + threadIdx.x;
    int g = (int)(i / E_);
    int e = (int)(i % E_);
    int dst = ei[(long)g * 2 * E_ + E_ + e];
    atomicAdd(&cnt[g * N_ + dst], 1);
}

// Wave-shuffle scan: 6 shfl steps intra-wave + 16-wave LDS combine.
// 4 barriers per 1024-chunk (was ~20 with Hillis-Steele).
__global__ void k_scan(int* __restrict__ cnt_cursor, int* __restrict__ row_ptr,
                       float* __restrict__ deg, SP sp)
{
    if ((int)blockIdx.x < sp.nsb) { stream_slice(sp, blockIdx.x); return; }
    int g = blockIdx.x - sp.nsb;
    __shared__ int swsum[16];
    __shared__ int s_off;
    const int lane = threadIdx.x & 63;
    const int wid = threadIdx.x >> 6;
    if (threadIdx.x == 0) s_off = 0;
    __syncthreads();
    for (int base = 0; base < N_; base += 1024) {
        int idx = g * N_ + base + threadIdx.x;
        int v = cnt_cursor[idx];
        int incl = v;
        #pragma unroll
        for (int d = 1; d < 64; d <<= 1) {
            int t = __shfl_up(incl, d);
            if (lane >= d) incl += t;
        }
        if (lane == 63) swsum[wid] = incl;
        __syncthreads();
        if (wid == 0 && lane < 16) {
            int sv = swsum[lane];
            #pragma unroll
            for (int d = 1; d < 16; d <<= 1) {
                int t = __shfl_up(sv, d);
                if (lane >= d) sv += t;
            }
            swsum[lane] = sv;
        }
        __syncthreads();
        int bse = s_off;
        int woff = wid ? swsum[wid - 1] : 0;
        int rp = bse + woff + incl - v;      // exclusive prefix
        row_ptr[g * (N_ + 1) + base + threadIdx.x] = rp;
        cnt_cursor[idx] = rp;
        deg[idx] = (float)(v > 1 ? v : 1);
        __syncthreads();
        if (threadIdx.x == 0) s_off = bse + swsum[15];
        __syncthreads();
    }
    if (threadIdx.x == 0) row_ptr[g * (N_ + 1) + N_] = s_off;
}

__global__ void k_fill(const int* __restrict__ ei, int* __restrict__ cursor,
                       int* __restrict__ csr_src, SP sp)
{
    if ((int)blockIdx.x < sp.nsb) { stream_slice(sp, blockIdx.x); return; }
    long i = (long)(blockIdx.x - sp.nsb) * blockDim.x + threadIdx.x;
    int g = (int)(i / E_);
    int e = (int)(i % E_);
    int src = ei[(long)g * 2 * E_ + e];
    int dst = ei[(long)g * 2 * E_ + E_ + e];
    int pos = atomicAdd(&cursor[g * N_ + dst], 1);
    csr_src[(long)g * E_ + pos] = src;
}

// ---------------------------------------------------------------------------
// Mean aggregation, XCD-pinned: graph g -> XCDs {2g,2g+1} via bid%8.
// One wave per node; 4 edges/iter (quarter-wave, 32B/lane), unroll 4
// -> 16 gather loads in flight per wave (latency-bound fix).
// ---------------------------------------------------------------------------
__global__ __launch_bounds__(256) void k_aggregate(
    const hb* __restrict__ x, const int* __restrict__ csr_src,
    const int* __restrict__ row_ptr, const float* __restrict__ deg,
    hb* __restrict__ m, SP sp)
{
    if ((int)blockIdx.x < sp.nsb) { stream_slice(sp, blockIdx.x); return; }
    int b = blockIdx.x - sp.nsb;
    int g = (b & 7) >> 1;
    int idx = ((b >> 3) << 1) | (b & 1);       // 0..N/4-1 within graph
    int node = idx * 4 + (threadIdx.x >> 6);
    int lane = threadIdx.x & 63;
    int qq = lane >> 4;
    int l16 = (lane & 15) * 16;
    const hb* xg = x + (long)g * N_ * F_;
    const int* rp = row_ptr + g * (N_ + 1);
    const int* cs = csr_src + (long)g * E_;
    int s = __builtin_amdgcn_readfirstlane(rp[node]);
    int e = __builtin_amdgcn_readfirstlane(rp[node + 1]);
    float a[16] = {};
    #pragma unroll 4
    for (int j = s; j < e; j += 4) {
        if (j + qq < e) {
            int src = cs[j + qq];
            const bf16x8* p = (const bf16x8*)(xg + (long)src * F_ + l16);
            bf16x8 v0 = p[0], v1 = p[1];
            #pragma unroll
            for (int q = 0; q < 8; ++q) a[q]     += b2f((unsigned short)v0[q]);
            #pragma unroll
            for (int q = 0; q < 8; ++q) a[q + 8] += b2f((unsigned short)v1[q]);
        }
    }
    #pragma unroll
    for (int q = 0; q < 16; ++q) {
        a[q] += __shfl_xor(a[q], 16);
        a[q] += __shfl_xor(a[q], 32);
    }
    if (qq == 0) {
        float inv = 1.0f / deg[g * N_ + node];
        bf16x8 lo, hi;
        #pragma unroll
        for (int q = 0; q < 8; ++q) { lo[q] = (short)f2bu(a[q] * inv); hi[q] = (short)f2bu(a[q + 8] * inv); }
        *(bf16x8*)(m + ((long)g * N_ + node) * F_ + l16) = lo;
        *(bf16x8*)(m + ((long)g * N_ + node) * F_ + l16 + 8) = hi;
    }
}

// ---------------------------------------------------------------------------
// bf16 MFMA NT GEMM, 1-D grid (stream blocks first), optional XCD pin,
// optional fused epilogues. 128x128 tile, 256 thr, BK=64, fp32 accum.
// LOGITS: relu(h)·W2 + b2 -> logits.  FUSEOUT: out2 = relu(resid + sum_g w_g feats_g).
// ---------------------------------------------------------------------------
template <bool DUAL, bool RELU, bool LOGITS, bool FUSEOUT, bool PIN>
__global__ __launch_bounds__(256) void k_mfma_nt(
    const hb* __restrict__ A1, const hb* __restrict__ B1,
    const hb* __restrict__ A2, const hb* __restrict__ B2,
    const float* __restrict__ bias, hb* __restrict__ C,
    int ncols, int nrows, int ng, int Nc, int K,
    long a_batch, long b_batch, long bias_batch, long c_batch,
    const float* __restrict__ W2, const float* __restrict__ b2,
    float* __restrict__ logits,
    const float* __restrict__ lgAll, const hb* __restrict__ fAll,
    float* __restrict__ o2,
    SP sp)
{
    if ((int)blockIdx.x < sp.nsb) { stream_slice(sp, blockIdx.x); return; }
    int b = blockIdx.x - sp.nsb;
    int g, col, row;
    if (PIN) {
        g = (b & 7) >> 1;
        int idx = ((b >> 3) << 1) | (b & 1);
        col = idx % ncols; row = idx / ncols;
    } else {
        col = b % ncols;
        int r2 = b / ncols;
        row = r2 % nrows; g = r2 / nrows;
    }
    const int row0 = row * 128;
    const int col0 = col * 128;

    const hb* A1p = A1 + (long)g * a_batch;
    const hb* B1p = B1 + (long)g * b_batch;
    const hb* A2p = nullptr;
    const hb* B2p = nullptr;
    if (DUAL) { A2p = A2 + (long)g * a_batch; B2p = B2 + (long)g * b_batch; }
    const float* biasp = bias + (long)g * bias_batch;
    hb* Cp = C + (long)g * c_batch;

    __shared__ hb As[128 * 64];
    __shared__ hb Bs[128 * 64];
    __shared__ float sLog[2][128];
    __shared__ float sW[128][4];

    const int tid = threadIdx.x;
    const int lane = tid & 63;
    const int wid = tid >> 6;
    const int wr = wid >> 1;
    const int wc = wid & 1;

    if (FUSEOUT) {
        if (tid < 128) {
            int rr = row0 + tid;
            float l0 = lgAll[rr], l1 = lgAll[N_ + rr], l2 = lgAll[2 * N_ + rr], l3 = lgAll[3 * N_ + rr];
            float mx = fmaxf(fmaxf(l0, l1), fmaxf(l2, l3));
            float e0 = expf(l0 - mx), e1 = expf(l1 - mx), e2 = expf(l2 - mx), e3 = expf(l3 - mx);
            float inv = 1.f / (e0 + e1 + e2 + e3);
            sW[tid][0] = e0 * inv; sW[tid][1] = e1 * inv;
            sW[tid][2] = e2 * inv; sW[tid][3] = e3 * inv;
        }
    }

    const int srow = tid >> 3;
    const int sk8  = (tid & 7) * 8;

    f32x4 acc[4][4] = {};

    const int fr  = lane & 15;
    const int fkq = (lane >> 4) * 8;

    const int npass = DUAL ? 2 : 1;
    for (int pass = 0; pass < npass; ++pass) {
        const hb* A = (DUAL && pass) ? A2p : A1p;
        const hb* B = (DUAL && pass) ? B2p : B1p;
        for (int k0 = 0; k0 < K; k0 += 64) {
            __syncthreads();
            #pragma unroll
            for (int c = 0; c < 4; ++c) {
                int r = c * 32 + srow;
                GLD_LDS16(A + (long)(row0 + r) * K + k0 + sk8, As + r * 64 + sk8);
                GLD_LDS16(B + (long)(col0 + r) * K + k0 + sk8, Bs + r * 64 + sk8);
            }
            __syncthreads();

            bf16x8 af[4][2], bfr[4][2];
            #pragma unroll
            for (int m = 0; m < 4; ++m)
                #pragma unroll
                for (int kk = 0; kk < 2; ++kk)
                    af[m][kk] = *(const bf16x8*)(As + (wr * 64 + m * 16 + fr) * 64 + kk * 32 + fkq);
            #pragma unroll
            for (int n = 0; n < 4; ++n)
                #pragma unroll
                for (int kk = 0; kk < 2; ++kk)
                    bfr[n][kk] = *(const bf16x8*)(Bs + (wc * 64 + n * 16 + fr) * 64 + kk * 32 + fkq);

            #pragma unroll
            for (int m = 0; m < 4; ++m)
                #pragma unroll
                for (int n = 0; n < 4; ++n)
                    #pragma unroll
                    for (int kk = 0; kk < 2; ++kk)
                        acc[m][n] = __builtin_amdgcn_mfma_f32_16x16x32_bf16(
                            af[m][kk], bfr[n][kk], acc[m][n], 0, 0, 0);
        }
    }

    const int r4 = (lane >> 4) * 4;
    const int cc = lane & 15;

    if (LOGITS) {
        float w2v[4], bv[4];
        #pragma unroll
        for (int n = 0; n < 4; ++n) {
            int c2 = wc * 64 + n * 16 + cc;
            w2v[n] = W2[c2];
            bv[n]  = biasp[c2];
        }
        #pragma unroll
        for (int m = 0; m < 4; ++m) {
            #pragma unroll
            for (int j = 0; j < 4; ++j) {
                float p = 0.f;
                #pragma unroll
                for (int n = 0; n < 4; ++n) {
                    float h = fmaxf(acc[m][n][j] + bv[n], 0.f);
                    p += h * w2v[n];
                }
                p += __shfl_xor(p, 1); p += __shfl_xor(p, 2);
                p += __shfl_xor(p, 4); p += __shfl_xor(p, 8);
                if (cc == 0) sLog[wc][wr * 64 + m * 16 + r4 + j] = p;
            }
        }
        __syncthreads();
        if (tid < 128)
            logits[(long)g * N_ + row0 + tid] = sLog[0][tid] + sLog[1][tid] + b2[0];
    } else if (FUSEOUT) {
        const unsigned short* fu = (const unsigned short*)fAll;
        #pragma unroll
        for (int m = 0; m < 4; ++m) {
            #pragma unroll
            for (int n = 0; n < 4; ++n) {
                int c2 = col0 + wc * 64 + n * 16 + cc;
                float bv = biasp[c2];
                #pragma unroll
                for (int j = 0; j < 4; ++j) {
                    int rl = wr * 64 + m * 16 + r4 + j;
                    int rr = row0 + rl;
                    float s = acc[m][n][j] + bv;
                    #pragma unroll
                    for (int gg = 0; gg < 4; ++gg)
                        s += sW[rl][gg] * b2f(fu[((long)gg * N_ + rr) * D_ + c2]);
                    __builtin_nontemporal_store(fmaxf(s, 0.f), o2 + (long)rr * D_ + c2);
                }
            }
        }
    } else {
        #pragma unroll
        for (int m = 0; m < 4; ++m) {
            #pragma unroll
            for (int n = 0; n < 4; ++n) {
                int c2 = col0 + wc * 64 + n * 16 + cc;
                float bv = biasp[c2];
                #pragma unroll
                for (int j = 0; j < 4; ++j) {
                    int rr = row0 + wr * 64 + m * 16 + r4 + j;
                    float v = acc[m][n][j] + bv;
                    if (RELU) v = fmaxf(v, 0.f);
                    Cp[(long)rr * Nc + c2] = __float2bfloat16(v);
                }
            }
        }
    }
}

// ---------------------------------------------------------------------------
extern "C" void kernel_launch(void* const* d_in, const int* in_sizes, int n_in,
                              void* d_out, int out_size, void* d_ws, size_t ws_size,
                              hipStream_t stream)
{
    const float* xs        = (const float*)d_in[0];
    const int*   ei        = (const int*)  d_in[1];
    const float* x_content = (const float*)d_in[2];
    const float* sage_Wl   = (const float*)d_in[3];
    const float* sage_bl   = (const float*)d_in[4];
    const float* sage_Wr   = (const float*)d_in[5];
    const float* lin_W     = (const float*)d_in[6];
    const float* lin_b     = (const float*)d_in[7];
    const float* att_W1    = (const float*)d_in[8];
    const float* att_b1    = (const float*)d_in[9];
    const float* att_W2    = (const float*)d_in[10];
    const float* att_b2    = (const float*)d_in[11];
    const float* res_W     = (const float*)d_in[12];
    const float* res_b     = (const float*)d_in[13];
    const float* fusion_w  = (const float*)d_in[14];
    const float* Cc        = (const float*)d_in[15];
    const float* Cs        = (const float*)d_in[16];

    float* out0 = (float*)d_out;                    // fusion_expression [N,N]
    float* out1 = out0 + (size_t)N_ * N_;           // x_content [N,F]
    float* out2 = out1 + (size_t)N_ * F_;           // structure_features [N,D]
    float* out3 = out2 + (size_t)N_ * D_;           // C_content [N,N]
    float* out4 = out3 + (size_t)N_ * N_;           // C_structure [N,N]

    char* w = (char*)d_ws;
    auto alloc = [&](size_t bytes) {
        char* p = w;
        w += (bytes + 255) & ~(size_t)255;
        return p;
    };
    hb* xsb   = (hb*)alloc((size_t)G_ * N_ * F_ * 2);
    hb* xA    = (hb*)alloc((size_t)G_ * N_ * F_ * 2);
    hb* xB    = (hb*)alloc((size_t)G_ * N_ * F_ * 2);
    hb* mb    = (hb*)alloc((size_t)G_ * N_ * F_ * 2);
    hb* feats = (hb*)alloc((size_t)G_ * N_ * D_ * 2);
    hb* Wlb   = (hb*)alloc((size_t)G_ * 3 * F_ * F_ * 2);
    hb* Wrb   = (hb*)alloc((size_t)G_ * 3 * F_ * F_ * 2);
    hb* linWb = (hb*)alloc((size_t)G_ * D_ * F_ * 2);
    hb* attWb = (hb*)alloc((size_t)A_ * D_ * 2);
    hb* resWb = (hb*)alloc((size_t)D_ * D_ * 2);
    float* logit = (float*)alloc((size_t)G_ * N_ * 4);
    float* deg   = (float*)alloc((size_t)G_ * N_ * 4);
    int*   rowp  = (int*)  alloc((size_t)G_ * (N_ + 1) * 4);
    int*   curs  = (int*)  alloc((size_t)G_ * N_ * 4);
    int*   csrc  = (int*)  alloc((size_t)G_ * E_ * 4);

    // streaming slice boundaries over U = N*N/4 f4 units (per-mille cumsum)
    // rebalanced: less on agg/scan (now faster), more on att/resid/tail
    const long U = (long)N_ * N_ / 4;
    // hosted: prep count scan fill agg0 sage0 agg1 sage1 agg2 sage2 feats att residfuse | tail
    const int cum[14] = {0, 85, 110, 130, 160, 255, 325, 420, 490, 585, 655, 745, 815, 950};
    long B[14];
    for (int i = 0; i < 14; ++i) B[i] = U * cum[i] / 1000;
    const int PREPB   = 512;
    const int SB_PREP = 512;
    const int SB_FLAT = 256;
    const int SB_GEMM = 256;
    const int TAILB   = 1024;
    auto mkSP = [&](int i, int nsb) {
        SP sp;
        sp.Cc = (const f4*)Cc; sp.Cs = (const f4*)Cs; sp.fw = fusion_w;
        sp.o0 = (f4*)out0; sp.o3 = (f4*)out3; sp.o4 = (f4*)out4;
        sp.ib = B[i]; sp.ie = (i == 13) ? U : B[i + 1]; sp.nsb = nsb;
        return sp;
    };
    SP tail = mkSP(13, TAILB);

    // 1) prologue: out1 copy + all bf16 conversions + curs zero (+ slice)
    k_prep<<<SB_PREP + PREPB, 256, 0, stream>>>(
        x_content, (f4*)out1, xs, (ushort4*)xsb,
        sage_Wl, (ushort4*)Wlb, sage_Wr, (ushort4*)Wrb,
        lin_W, (ushort4*)linWb, att_W1, (ushort4*)attWb, res_W, (ushort4*)resWb,
        (i4*)curs, PREPB, mkSP(0, SB_PREP));

    // 2) CSR build (+ stream slices, stream blocks first)
    k_count<<<SB_FLAT + G_ * E_ / 256, 256, 0, stream>>>(ei, curs, mkSP(1, SB_FLAT));
    k_scan<<<SB_FLAT + G_, 1024, 0, stream>>>(curs, rowp, deg, mkSP(2, SB_FLAT));
    k_fill<<<SB_FLAT + G_ * E_ / 256, 256, 0, stream>>>(ei, curs, csrc, mkSP(3, SB_FLAT));

    // 3) GNN: 3 layers, ping-pong xsb -> xA -> xB -> xA (XCD-pinned)
    const hb* xin = xsb;
    hb* xout = xA;
    for (int layer = 0; layer < 3; ++layer) {
        k_aggregate<<<SB_FLAT + G_ * N_ / 4, 256, 0, stream>>>(
            xin, csrc, rowp, deg, mb, mkSP(4 + 2 * layer, SB_FLAT));
        k_mfma_nt<true, true, false, false, true>
            <<<SB_GEMM + (F_ / 128) * (N_ / 128) * G_, 256, 0, stream>>>(
            mb, Wlb + (size_t)layer * F_ * F_,
            xin, Wrb + (size_t)layer * F_ * F_,
            sage_bl + (size_t)layer * F_, xout,
            F_ / 128, N_ / 128, G_, F_, F_,
            (long)N_ * F_, (long)3 * F_ * F_, (long)3 * F_, (long)N_ * F_,
            nullptr, nullptr, nullptr, nullptr, nullptr, nullptr,
            mkSP(5 + 2 * layer, SB_GEMM));
        xin = xout;
        xout = (layer == 0) ? xB : xA;
    }
    const hb* xg = xA;  // after layer 2 result lands in xA

    // 4) feats = xg @ lin_W^T + lin_b   [G,N,D] bf16  (pinned)
    k_mfma_nt<false, false, false, false, true>
        <<<SB_GEMM + (D_ / 128) * (N_ / 128) * G_, 256, 0, stream>>>(
        xg, linWb, nullptr, nullptr, lin_b, feats,
        D_ / 128, N_ / 128, G_, D_, F_,
        (long)N_ * F_, (long)D_ * F_, (long)D_, (long)N_ * D_,
        nullptr, nullptr, nullptr, nullptr, nullptr, nullptr,
        mkSP(10, SB_GEMM));

    // 5) logits = relu(feats @ att_W1^T + att_b1) . W2 + b2  (pinned, fused)
    k_mfma_nt<false, true, true, false, true>
        <<<SB_GEMM + (A_ / 128) * (N_ / 128) * G_, 256, 0, stream>>>(
        feats, attWb, nullptr, nullptr, att_b1, nullptr,
        A_ / 128, N_ / 128, G_, A_, D_,
        (long)N_ * D_, 0L, 0L, 0L,
        att_W2, att_b2, logit, nullptr, nullptr, nullptr,
        mkSP(11, SB_GEMM));

    // 6) out2 = relu(feats[0] @ res_W^T + res_b + sum_g w_g feats_g)
    k_mfma_nt<false, false, false, true, false>
        <<<SB_GEMM + (D_ / 128) * (N_ / 128) * 1, 256, 0, stream>>>(
        feats, resWb, nullptr, nullptr, res_b, nullptr,
        D_ / 128, N_ / 128, 1, D_, D_,
        0L, 0L, 0L, 0L,
        nullptr, nullptr, nullptr, logit, feats, out2,
        mkSP(12, SB_GEMM));

    // 7) remaining streaming at full grid
    k_tail<<<TAILB, 256, 0, stream>>>(tail);
}

// Round 13
// 405.692 us; speedup vs baseline: 1.6050x; 1.0424x over previous
//
#include <hip/hip_runtime.h>
#include <hip/hip_bf16.h>

// Problem constants (from reference)
constexpr int N_ = 6144;      // nodes
constexpr int E_ = 196608;    // edges per graph
constexpr int F_ = 256;       // feature dim (== H)
constexpr int D_ = 512;       // fusion dim
constexpr int G_ = 4;         // graphs
constexpr int A_ = 128;       // attention bottleneck

typedef short bf16x8 __attribute__((ext_vector_type(8)));
typedef float f32x4 __attribute__((ext_vector_type(4)));
typedef float f4 __attribute__((ext_vector_type(4)));
typedef __hip_bfloat16 hb;

__device__ inline float b2f(unsigned short u) {
    union { unsigned u32; float f; } x; x.u32 = ((unsigned)u) << 16; return x.f;
}
__device__ inline unsigned short f2bu(float f) {
    hb b = __float2bfloat16(f);
    return *reinterpret_cast<unsigned short*>(&b);
}
__device__ inline ushort4 cvt4(f4 x) {
    ushort4 o;
    o.x = f2bu(x[0]); o.y = f2bu(x[1]); o.z = f2bu(x[2]); o.w = f2bu(x[3]);
    return o;
}

#define GLD_LDS16(gp, lp) \
    __builtin_amdgcn_global_load_lds((const __attribute__((address_space(1))) void*)(gp), \
                                     (__attribute__((address_space(3))) void*)(lp), 16, 0, 0)

// ---------------------------------------------------------------------------
// Streaming side-work (fusion): o0 = w0*Cc + w1*Cs ; o3 = Cc ; o4 = Cs.
// Disjoint [ib,ie) slices over N*N/4 f4s, hosted by the FIRST nsb blocks of
// each hybrid kernel. ILP-4 grid-stride (best measured variant).
// ---------------------------------------------------------------------------
struct SP {
    const f4* Cc; const f4* Cs; const float* fw;
    f4* o0; f4* o3; f4* o4;
    long ib; long ie; int nsb;
};

__device__ void stream_slice(const SP sp, int sb)
{
    float fa = sp.fw[0], fb = sp.fw[1];
    float mx = fmaxf(fa, fb);
    float ea = expf(fa - mx), eb = expf(fb - mx);
    float w0 = ea / (ea + eb), w1 = eb / (ea + eb);
    const long S = (long)sp.nsb * blockDim.x;
    long i = sp.ib + (long)sb * blockDim.x + threadIdx.x;
    for (; i + 3 * S < sp.ie; i += 4 * S) {
        f4 a0 = __builtin_nontemporal_load(sp.Cc + i);
        f4 b0 = __builtin_nontemporal_load(sp.Cs + i);
        f4 a1 = __builtin_nontemporal_load(sp.Cc + i + S);
        f4 b1 = __builtin_nontemporal_load(sp.Cs + i + S);
        f4 a2 = __builtin_nontemporal_load(sp.Cc + i + 2 * S);
        f4 b2 = __builtin_nontemporal_load(sp.Cs + i + 2 * S);
        f4 a3 = __builtin_nontemporal_load(sp.Cc + i + 3 * S);
        f4 b3 = __builtin_nontemporal_load(sp.Cs + i + 3 * S);
        __builtin_nontemporal_store(a0, sp.o3 + i);
        __builtin_nontemporal_store(b0, sp.o4 + i);
        __builtin_nontemporal_store(w0 * a0 + w1 * b0, sp.o0 + i);
        __builtin_nontemporal_store(a1, sp.o3 + i + S);
        __builtin_nontemporal_store(b1, sp.o4 + i + S);
        __builtin_nontemporal_store(w0 * a1 + w1 * b1, sp.o0 + i + S);
        __builtin_nontemporal_store(a2, sp.o3 + i + 2 * S);
        __builtin_nontemporal_store(b2, sp.o4 + i + 2 * S);
        __builtin_nontemporal_store(w0 * a2 + w1 * b2, sp.o0 + i + 2 * S);
        __builtin_nontemporal_store(a3, sp.o3 + i + 3 * S);
        __builtin_nontemporal_store(b3, sp.o4 + i + 3 * S);
        __builtin_nontemporal_store(w0 * a3 + w1 * b3, sp.o0 + i + 3 * S);
    }
    for (; i < sp.ie; i += S) {
        f4 a = __builtin_nontemporal_load(sp.Cc + i);
        f4 b = __builtin_nontemporal_load(sp.Cs + i);
        __builtin_nontemporal_store(a, sp.o3 + i);
        __builtin_nontemporal_store(b, sp.o4 + i);
        __builtin_nontemporal_store(w0 * a + w1 * b, sp.o0 + i);
    }
}

__global__ void k_tail(SP sp) { stream_slice(sp, blockIdx.x); }

// ---------------------------------------------------------------------------
// Prologue (fused with count): out1 = copy(x_content); fp32->bf16 converts;
// degree count atomics. curs is zeroed by a memset BEFORE this kernel.
// Copy and xs-convert loops are ILP-4. Blocks [0,nsb) stream.
// ---------------------------------------------------------------------------
__global__ void k_prep(const float* __restrict__ xc, f4* __restrict__ o1,
                       const float* __restrict__ xs, ushort4* __restrict__ xsb,
                       const float* __restrict__ Wl, ushort4* __restrict__ Wlb,
                       const float* __restrict__ Wr, ushort4* __restrict__ Wrb,
                       const float* __restrict__ lin, ushort4* __restrict__ linb,
                       const float* __restrict__ aw, ushort4* __restrict__ awb,
                       const float* __restrict__ rw, ushort4* __restrict__ rwb,
                       const int* __restrict__ ei, int* __restrict__ cnt,
                       int PB, SP sp)
{
    if ((int)blockIdx.x < sp.nsb) { stream_slice(sp, blockIdx.x); return; }
    const int cb = blockIdx.x - sp.nsb;
    const long S = (long)PB * 256;
    const long t0 = (long)cb * 256 + threadIdx.x;

    // region 1: copy x_content -> out1 (ILP-4, nontemporal)
    {
        const long n = (long)N_ * F_ / 4;
        const f4* src = (const f4*)xc;
        long i = t0;
        for (; i + 3 * S < n; i += 4 * S) {
            f4 x0 = __builtin_nontemporal_load(src + i);
            f4 x1 = __builtin_nontemporal_load(src + i + S);
            f4 x2 = __builtin_nontemporal_load(src + i + 2 * S);
            f4 x3 = __builtin_nontemporal_load(src + i + 3 * S);
            __builtin_nontemporal_store(x0, o1 + i);
            __builtin_nontemporal_store(x1, o1 + i + S);
            __builtin_nontemporal_store(x2, o1 + i + 2 * S);
            __builtin_nontemporal_store(x3, o1 + i + 3 * S);
        }
        for (; i < n; i += S)
            __builtin_nontemporal_store(__builtin_nontemporal_load(src + i), o1 + i);
    }
    // region 2: xs -> xsb bf16 (ILP-4)
    {
        const long n = (long)G_ * N_ * F_ / 4;
        const f4* src = (const f4*)xs;
        long i = t0;
        for (; i + 3 * S < n; i += 4 * S) {
            f4 x0 = src[i];
            f4 x1 = src[i + S];
            f4 x2 = src[i + 2 * S];
            f4 x3 = src[i + 3 * S];
            xsb[i] = cvt4(x0);
            xsb[i + S] = cvt4(x1);
            xsb[i + 2 * S] = cvt4(x2);
            xsb[i + 3 * S] = cvt4(x3);
        }
        for (; i < n; i += S) xsb[i] = cvt4(src[i]);
    }
    // region 3: weights concat (small, ILP-1 select)
    {
        const long n2 = (long)G_ * 3 * F_ * F_ / 4;
        const long n4 = (long)G_ * D_ * F_ / 4;
        const long n5 = (long)A_ * D_ / 4;
        const long n6 = (long)D_ * D_ / 4;
        const long T = 2 * n2 + n4 + n5 + n6;
        for (long u = t0; u < T; u += S) {
            long v = u;
            const float* s; ushort4* d;
            if (v < n2) { s = Wl; d = Wlb; }
            else {
                v -= n2;
                if (v < n2) { s = Wr; d = Wrb; }
                else {
                    v -= n2;
                    if (v < n4) { s = lin; d = linb; }
                    else {
                        v -= n4;
                        if (v < n5) { s = aw; d = awb; }
                        else { v -= n5; s = rw; d = rwb; }
                    }
                }
            }
            d[v] = cvt4(((const f4*)s)[v]);
        }
    }
    // region 4: degree count (independent of conversions)
    {
        for (long i = t0; i < (long)G_ * E_; i += S) {
            int g = (int)(i / E_);
            int e = (int)(i % E_);
            int dst = ei[(long)g * 2 * E_ + E_ + e];
            atomicAdd(&cnt[g * N_ + dst], 1);
        }
    }
}

// ---------------------------------------------------------------------------
// CSR: wave-shuffle scan + fill (stream blocks first in each grid)
// ---------------------------------------------------------------------------
__global__ void k_scan(int* __restrict__ cnt_cursor, int* __restrict__ row_ptr,
                       float* __restrict__ deg, SP sp)
{
    if ((int)blockIdx.x < sp.nsb) { stream_slice(sp, blockIdx.x); return; }
    int g = blockIdx.x - sp.nsb;
    __shared__ int swsum[16];
    __shared__ int s_off;
    const int lane = threadIdx.x & 63;
    const int wid = threadIdx.x >> 6;
    if (threadIdx.x == 0) s_off = 0;
    __syncthreads();
    for (int base = 0; base < N_; base += 1024) {
        int idx = g * N_ + base + threadIdx.x;
        int v = cnt_cursor[idx];
        int incl = v;
        #pragma unroll
        for (int d = 1; d < 64; d <<= 1) {
            int t = __shfl_up(incl, d);
            if (lane >= d) incl += t;
        }
        if (lane == 63) swsum[wid] = incl;
        __syncthreads();
        if (wid == 0 && lane < 16) {
            int sv = swsum[lane];
            #pragma unroll
            for (int d = 1; d < 16; d <<= 1) {
                int t = __shfl_up(sv, d);
                if (lane >= d) sv += t;
            }
            swsum[lane] = sv;
        }
        __syncthreads();
        int bse = s_off;
        int woff = wid ? swsum[wid - 1] : 0;
        int rp = bse + woff + incl - v;      // exclusive prefix
        row_ptr[g * (N_ + 1) + base + threadIdx.x] = rp;
        cnt_cursor[idx] = rp;
        deg[idx] = (float)(v > 1 ? v : 1);
        __syncthreads();
        if (threadIdx.x == 0) s_off = bse + swsum[15];
        __syncthreads();
    }
    if (threadIdx.x == 0) row_ptr[g * (N_ + 1) + N_] = s_off;
}

__global__ void k_fill(const int* __restrict__ ei, int* __restrict__ cursor,
                       int* __restrict__ csr_src, SP sp)
{
    if ((int)blockIdx.x < sp.nsb) { stream_slice(sp, blockIdx.x); return; }
    long i = (long)(blockIdx.x - sp.nsb) * blockDim.x + threadIdx.x;
    int g = (int)(i / E_);
    int e = (int)(i % E_);
    int src = ei[(long)g * 2 * E_ + e];
    int dst = ei[(long)g * 2 * E_ + E_ + e];
    int pos = atomicAdd(&cursor[g * N_ + dst], 1);
    csr_src[(long)g * E_ + pos] = src;
}

// ---------------------------------------------------------------------------
// Mean aggregation, XCD-pinned. One wave per node; 4 edges/iter, unroll 4.
// ---------------------------------------------------------------------------
__global__ __launch_bounds__(256) void k_aggregate(
    const hb* __restrict__ x, const int* __restrict__ csr_src,
    const int* __restrict__ row_ptr, const float* __restrict__ deg,
    hb* __restrict__ m, SP sp)
{
    if ((int)blockIdx.x < sp.nsb) { stream_slice(sp, blockIdx.x); return; }
    int b = blockIdx.x - sp.nsb;
    int g = (b & 7) >> 1;
    int idx = ((b >> 3) << 1) | (b & 1);
    int node = idx * 4 + (threadIdx.x >> 6);
    int lane = threadIdx.x & 63;
    int qq = lane >> 4;
    int l16 = (lane & 15) * 16;
    const hb* xg = x + (long)g * N_ * F_;
    const int* rp = row_ptr + g * (N_ + 1);
    const int* cs = csr_src + (long)g * E_;
    int s = __builtin_amdgcn_readfirstlane(rp[node]);
    int e = __builtin_amdgcn_readfirstlane(rp[node + 1]);
    float a[16] = {};
    #pragma unroll 4
    for (int j = s; j < e; j += 4) {
        if (j + qq < e) {
            int src = cs[j + qq];
            const bf16x8* p = (const bf16x8*)(xg + (long)src * F_ + l16);
            bf16x8 v0 = p[0], v1 = p[1];
            #pragma unroll
            for (int q = 0; q < 8; ++q) a[q]     += b2f((unsigned short)v0[q]);
            #pragma unroll
            for (int q = 0; q < 8; ++q) a[q + 8] += b2f((unsigned short)v1[q]);
        }
    }
    #pragma unroll
    for (int q = 0; q < 16; ++q) {
        a[q] += __shfl_xor(a[q], 16);
        a[q] += __shfl_xor(a[q], 32);
    }
    if (qq == 0) {
        float inv = 1.0f / deg[g * N_ + node];
        bf16x8 lo, hi;
        #pragma unroll
        for (int q = 0; q < 8; ++q) { lo[q] = (short)f2bu(a[q] * inv); hi[q] = (short)f2bu(a[q + 8] * inv); }
        *(bf16x8*)(m + ((long)g * N_ + node) * F_ + l16) = lo;
        *(bf16x8*)(m + ((long)g * N_ + node) * F_ + l16 + 8) = hi;
    }
}

// ---------------------------------------------------------------------------
// SAGE dual GEMM, 128x64 tile (768 blocks -> 3/CU occupancy), XCD-pinned.
// C[row,col] = relu(mb@Wl^T + xin@Wr^T + bl), all per-graph. K=F=256.
// ---------------------------------------------------------------------------
__global__ __launch_bounds__(256) void k_sage64(
    const hb* __restrict__ A1, const hb* __restrict__ B1,
    const hb* __restrict__ A2, const hb* __restrict__ B2,
    const float* __restrict__ bias, hb* __restrict__ C, SP sp)
{
    if ((int)blockIdx.x < sp.nsb) { stream_slice(sp, blockIdx.x); return; }
    int b = blockIdx.x - sp.nsb;
    int g = (b & 7) >> 1;
    int idx = ((b >> 3) << 1) | (b & 1);   // 0..191
    int col = idx & 3, row = idx >> 2;     // 4 col-tiles, 48 row-tiles
    const int row0 = row * 128, col0 = col * 64;

    const hb* A1p = A1 + (long)g * N_ * F_;
    const hb* A2p = A2 + (long)g * N_ * F_;
    const hb* B1p = B1 + (long)g * 3 * F_ * F_;
    const hb* B2p = B2 + (long)g * 3 * F_ * F_;
    const float* biasp = bias + (long)g * 3 * F_;
    hb* Cp = C + (long)g * N_ * F_;

    __shared__ hb As[128 * 64];
    __shared__ hb Bs[64 * 64];

    const int tid = threadIdx.x;
    const int lane = tid & 63;
    const int wid = tid >> 6;
    const int wr = wid >> 1, wc = wid & 1;
    const int srow = tid >> 3;          // 0..31
    const int sk8 = (tid & 7) * 8;
    const int fr = lane & 15;
    const int fkq = (lane >> 4) * 8;

    f32x4 acc[4][2] = {};

    #pragma unroll
    for (int pass = 0; pass < 2; ++pass) {
        const hb* A = pass ? A2p : A1p;
        const hb* B = pass ? B2p : B1p;
        for (int k0 = 0; k0 < F_; k0 += 64) {
            __syncthreads();
            #pragma unroll
            for (int c = 0; c < 4; ++c) {
                int r = c * 32 + srow;
                GLD_LDS16(A + (long)(row0 + r) * F_ + k0 + sk8, As + r * 64 + sk8);
            }
            #pragma unroll
            for (int c = 0; c < 2; ++c) {
                int r = c * 32 + srow;
                GLD_LDS16(B + (long)(col0 + r) * F_ + k0 + sk8, Bs + r * 64 + sk8);
            }
            __syncthreads();

            bf16x8 af[4][2], bq[2][2];
            #pragma unroll
            for (int m = 0; m < 4; ++m)
                #pragma unroll
                for (int kk = 0; kk < 2; ++kk)
                    af[m][kk] = *(const bf16x8*)(As + (wr * 64 + m * 16 + fr) * 64 + kk * 32 + fkq);
            #pragma unroll
            for (int n = 0; n < 2; ++n)
                #pragma unroll
                for (int kk = 0; kk < 2; ++kk)
                    bq[n][kk] = *(const bf16x8*)(Bs + (wc * 32 + n * 16 + fr) * 64 + kk * 32 + fkq);

            #pragma unroll
            for (int m = 0; m < 4; ++m)
                #pragma unroll
                for (int n = 0; n < 2; ++n)
                    #pragma unroll
                    for (int kk = 0; kk < 2; ++kk)
                        acc[m][n] = __builtin_amdgcn_mfma_f32_16x16x32_bf16(
                            af[m][kk], bq[n][kk], acc[m][n], 0, 0, 0);
        }
    }

    const int r4 = (lane >> 4) * 4;
    const int cc = lane & 15;
    #pragma unroll
    for (int m = 0; m < 4; ++m) {
        #pragma unroll
        for (int n = 0; n < 2; ++n) {
            int c2 = col0 + wc * 32 + n * 16 + cc;
            float bv = biasp[c2];
            #pragma unroll
            for (int j = 0; j < 4; ++j) {
                int rr = row0 + wr * 64 + m * 16 + r4 + j;
                float v = fmaxf(acc[m][n][j] + bv, 0.f);
                Cp[(long)rr * F_ + c2] = __float2bfloat16(v);
            }
        }
    }
}

// ---------------------------------------------------------------------------
// bf16 MFMA NT GEMM 128x128 (feats / att+logits / resid+fuseout).
// ---------------------------------------------------------------------------
template <bool RELU, bool LOGITS, bool FUSEOUT, bool PIN>
__global__ __launch_bounds__(256) void k_mfma_nt(
    const hb* __restrict__ A1, const hb* __restrict__ B1,
    const float* __restrict__ bias, hb* __restrict__ C,
    int ncols, int nrows, int ng, int Nc, int K,
    long a_batch, long b_batch, long bias_batch, long c_batch,
    const float* __restrict__ W2, const float* __restrict__ b2,
    float* __restrict__ logits,
    const float* __restrict__ lgAll, const hb* __restrict__ fAll,
    float* __restrict__ o2,
    SP sp)
{
    if ((int)blockIdx.x < sp.nsb) { stream_slice(sp, blockIdx.x); return; }
    int b = blockIdx.x - sp.nsb;
    int g, col, row;
    if (PIN) {
        g = (b & 7) >> 1;
        int idx = ((b >> 3) << 1) | (b & 1);
        col = idx % ncols; row = idx / ncols;
    } else {
        col = b % ncols;
        int r2 = b / ncols;
        row = r2 % nrows; g = r2 / nrows;
    }
    const int row0 = row * 128;
    const int col0 = col * 128;

    const hb* A1p = A1 + (long)g * a_batch;
    const hb* B1p = B1 + (long)g * b_batch;
    const float* biasp = bias + (long)g * bias_batch;
    hb* Cp = C + (long)g * c_batch;

    __shared__ hb As[128 * 64];
    __shared__ hb Bs[128 * 64];
    __shared__ float sLog[2][128];
    __shared__ float sW[128][4];

    const int tid = threadIdx.x;
    const int lane = tid & 63;
    const int wid = tid >> 6;
    const int wr = wid >> 1;
    const int wc = wid & 1;

    if (FUSEOUT) {
        if (tid < 128) {
            int rr = row0 + tid;
            float l0 = lgAll[rr], l1 = lgAll[N_ + rr], l2 = lgAll[2 * N_ + rr], l3 = lgAll[3 * N_ + rr];
            float mx = fmaxf(fmaxf(l0, l1), fmaxf(l2, l3));
            float e0 = expf(l0 - mx), e1 = expf(l1 - mx), e2 = expf(l2 - mx), e3 = expf(l3 - mx);
            float inv = 1.f / (e0 + e1 + e2 + e3);
            sW[tid][0] = e0 * inv; sW[tid][1] = e1 * inv;
            sW[tid][2] = e2 * inv; sW[tid][3] = e3 * inv;
        }
    }

    const int srow = tid >> 3;
    const int sk8  = (tid & 7) * 8;

    f32x4 acc[4][4] = {};

    const int fr  = lane & 15;
    const int fkq = (lane >> 4) * 8;

    for (int k0 = 0; k0 < K; k0 += 64) {
        __syncthreads();
        #pragma unroll
        for (int c = 0; c < 4; ++c) {
            int r = c * 32 + srow;
            GLD_LDS16(A1p + (long)(row0 + r) * K + k0 + sk8, As + r * 64 + sk8);
            GLD_LDS16(B1p + (long)(col0 + r) * K + k0 + sk8, Bs + r * 64 + sk8);
        }
        __syncthreads();

        bf16x8 af[4][2], bfr[4][2];
        #pragma unroll
        for (int m = 0; m < 4; ++m)
            #pragma unroll
            for (int kk = 0; kk < 2; ++kk)
                af[m][kk] = *(const bf16x8*)(As + (wr * 64 + m * 16 + fr) * 64 + kk * 32 + fkq);
        #pragma unroll
        for (int n = 0; n < 4; ++n)
            #pragma unroll
            for (int kk = 0; kk < 2; ++kk)
                bfr[n][kk] = *(const bf16x8*)(Bs + (wc * 64 + n * 16 + fr) * 64 + kk * 32 + fkq);

        #pragma unroll
        for (int m = 0; m < 4; ++m)
            #pragma unroll
            for (int n = 0; n < 4; ++n)
                #pragma unroll
                for (int kk = 0; kk < 2; ++kk)
                    acc[m][n] = __builtin_amdgcn_mfma_f32_16x16x32_bf16(
                        af[m][kk], bfr[n][kk], acc[m][n], 0, 0, 0);
    }

    const int r4 = (lane >> 4) * 4;
    const int cc = lane & 15;

    if (LOGITS) {
        float w2v[4], bv[4];
        #pragma unroll
        for (int n = 0; n < 4; ++n) {
            int c2 = wc * 64 + n * 16 + cc;
            w2v[n] = W2[c2];
            bv[n]  = biasp[c2];
        }
        #pragma unroll
        for (int m = 0; m < 4; ++m) {
            #pragma unroll
            for (int j = 0; j < 4; ++j) {
                float p = 0.f;
                #pragma unroll
                for (int n = 0; n < 4; ++n) {
                    float h = fmaxf(acc[m][n][j] + bv[n], 0.f);
                    p += h * w2v[n];
                }
                p += __shfl_xor(p, 1); p += __shfl_xor(p, 2);
                p += __shfl_xor(p, 4); p += __shfl_xor(p, 8);
                if (cc == 0) sLog[wc][wr * 64 + m * 16 + r4 + j] = p;
            }
        }
        __syncthreads();
        if (tid < 128)
            logits[(long)g * N_ + row0 + tid] = sLog[0][tid] + sLog[1][tid] + b2[0];
    } else if (FUSEOUT) {
        const unsigned short* fu = (const unsigned short*)fAll;
        #pragma unroll
        for (int m = 0; m < 4; ++m) {
            #pragma unroll
            for (int n = 0; n < 4; ++n) {
                int c2 = col0 + wc * 64 + n * 16 + cc;
                float bv = biasp[c2];
                #pragma unroll
                for (int j = 0; j < 4; ++j) {
                    int rl = wr * 64 + m * 16 + r4 + j;
                    int rr = row0 + rl;
                    float s = acc[m][n][j] + bv;
                    #pragma unroll
                    for (int gg = 0; gg < 4; ++gg)
                        s += sW[rl][gg] * b2f(fu[((long)gg * N_ + rr) * D_ + c2]);
                    __builtin_nontemporal_store(fmaxf(s, 0.f), o2 + (long)rr * D_ + c2);
                }
            }
        }
    } else {
        #pragma unroll
        for (int m = 0; m < 4; ++m) {
            #pragma unroll
            for (int n = 0; n < 4; ++n) {
                int c2 = col0 + wc * 64 + n * 16 + cc;
                float bv = biasp[c2];
                #pragma unroll
                for (int j = 0; j < 4; ++j) {
                    int rr = row0 + wr * 64 + m * 16 + r4 + j;
                    float v = acc[m][n][j] + bv;
                    if (RELU) v = fmaxf(v, 0.f);
                    Cp[(long)rr * Nc + c2] = __float2bfloat16(v);
                }
            }
        }
    }
}

// ---------------------------------------------------------------------------
extern "C" void kernel_launch(void* const* d_in, const int* in_sizes, int n_in,
                              void* d_out, int out_size, void* d_ws, size_t ws_size,
                              hipStream_t stream)
{
    const float* xs        = (const float*)d_in[0];
    const int*   ei        = (const int*)  d_in[1];
    const float* x_content = (const float*)d_in[2];
    const float* sage_Wl   = (const float*)d_in[3];
    const float* sage_bl   = (const float*)d_in[4];
    const float* sage_Wr   = (const float*)d_in[5];
    const float* lin_W     = (const float*)d_in[6];
    const float* lin_b     = (const float*)d_in[7];
    const float* att_W1    = (const float*)d_in[8];
    const float* att_b1    = (const float*)d_in[9];
    const float* att_W2    = (const float*)d_in[10];
    const float* att_b2    = (const float*)d_in[11];
    const float* res_W     = (const float*)d_in[12];
    const float* res_b     = (const float*)d_in[13];
    const float* fusion_w  = (const float*)d_in[14];
    const float* Cc        = (const float*)d_in[15];
    const float* Cs        = (const float*)d_in[16];

    float* out0 = (float*)d_out;                    // fusion_expression [N,N]
    float* out1 = out0 + (size_t)N_ * N_;           // x_content [N,F]
    float* out2 = out1 + (size_t)N_ * F_;           // structure_features [N,D]
    float* out3 = out2 + (size_t)N_ * D_;           // C_content [N,N]
    float* out4 = out3 + (size_t)N_ * N_;           // C_structure [N,N]

    char* w = (char*)d_ws;
    auto alloc = [&](size_t bytes) {
        char* p = w;
        w += (bytes + 255) & ~(size_t)255;
        return p;
    };
    hb* xsb   = (hb*)alloc((size_t)G_ * N_ * F_ * 2);
    hb* xA    = (hb*)alloc((size_t)G_ * N_ * F_ * 2);
    hb* xB    = (hb*)alloc((size_t)G_ * N_ * F_ * 2);
    hb* mb    = (hb*)alloc((size_t)G_ * N_ * F_ * 2);
    hb* feats = (hb*)alloc((size_t)G_ * N_ * D_ * 2);
    hb* Wlb   = (hb*)alloc((size_t)G_ * 3 * F_ * F_ * 2);
    hb* Wrb   = (hb*)alloc((size_t)G_ * 3 * F_ * F_ * 2);
    hb* linWb = (hb*)alloc((size_t)G_ * D_ * F_ * 2);
    hb* attWb = (hb*)alloc((size_t)A_ * D_ * 2);
    hb* resWb = (hb*)alloc((size_t)D_ * D_ * 2);
    float* logit = (float*)alloc((size_t)G_ * N_ * 4);
    float* deg   = (float*)alloc((size_t)G_ * N_ * 4);
    int*   rowp  = (int*)  alloc((size_t)G_ * (N_ + 1) * 4);
    int*   curs  = (int*)  alloc((size_t)G_ * N_ * 4);
    int*   csrc  = (int*)  alloc((size_t)G_ * E_ * 4);

    // streaming slice boundaries over U = N*N/4 f4 units (per-mille cumsum)
    // hosted: prep scan fill agg0 sage0 agg1 sage1 agg2 sage2 feats att resid | tail
    const long U = (long)N_ * N_ / 4;
    const int cum[14] = {0, 100, 120, 150, 235, 300, 385, 450, 535, 600, 680, 760, 950, 1000};
    long B[14];
    for (int i = 0; i < 14; ++i) B[i] = U * cum[i] / 1000;
    const int PREPB   = 768;
    const int SB_PREP = 448;
    const int SB_FLAT = 256;
    const int SB_GEMM = 256;
    const int TAILB   = 1024;
    auto mkSP = [&](int i, int nsb) {
        SP sp;
        sp.Cc = (const f4*)Cc; sp.Cs = (const f4*)Cs; sp.fw = fusion_w;
        sp.o0 = (f4*)out0; sp.o3 = (f4*)out3; sp.o4 = (f4*)out4;
        sp.ib = B[i]; sp.ie = B[i + 1]; sp.nsb = nsb;
        return sp;
    };
    SP tail;
    tail.Cc = (const f4*)Cc; tail.Cs = (const f4*)Cs; tail.fw = fusion_w;
    tail.o0 = (f4*)out0; tail.o3 = (f4*)out3; tail.o4 = (f4*)out4;
    tail.ib = B[12]; tail.ie = U; tail.nsb = TAILB;

    // 0) zero degree-count buffer (needed before fused count in prep)
    hipMemsetAsync(curs, 0, (size_t)G_ * N_ * 4, stream);

    // 1) prologue: copy + converts + count (+ slice)
    k_prep<<<SB_PREP + PREPB, 256, 0, stream>>>(
        x_content, (f4*)out1, xs, (ushort4*)xsb,
        sage_Wl, (ushort4*)Wlb, sage_Wr, (ushort4*)Wrb,
        lin_W, (ushort4*)linWb, att_W1, (ushort4*)attWb, res_W, (ushort4*)resWb,
        ei, curs, PREPB, mkSP(0, SB_PREP));

    // 2) CSR scan + fill
    k_scan<<<SB_FLAT + G_, 1024, 0, stream>>>(curs, rowp, deg, mkSP(1, SB_FLAT));
    k_fill<<<SB_FLAT + G_ * E_ / 256, 256, 0, stream>>>(ei, curs, csrc, mkSP(2, SB_FLAT));

    // 3) GNN: 3 layers, ping-pong xsb -> xA -> xB -> xA (XCD-pinned)
    const hb* xin = xsb;
    hb* xout = xA;
    for (int layer = 0; layer < 3; ++layer) {
        k_aggregate<<<SB_FLAT + G_ * N_ / 4, 256, 0, stream>>>(
            xin, csrc, rowp, deg, mb, mkSP(3 + 2 * layer, SB_FLAT));
        k_sage64<<<SB_GEMM + 4 * (N_ / 128) * G_, 256, 0, stream>>>(
            mb, Wlb + (size_t)layer * F_ * F_,
            xin, Wrb + (size_t)layer * F_ * F_,
            sage_bl + (size_t)layer * F_, xout,
            mkSP(4 + 2 * layer, SB_GEMM));
        xin = xout;
        xout = (layer == 0) ? xB : xA;
    }
    const hb* xg = xA;  // after layer 2 result lands in xA

    // 4) feats = xg @ lin_W^T + lin_b   [G,N,D] bf16  (pinned)
    k_mfma_nt<false, false, false, true>
        <<<SB_GEMM + (D_ / 128) * (N_ / 128) * G_, 256, 0, stream>>>(
        xg, linWb, lin_b, feats,
        D_ / 128, N_ / 128, G_, D_, F_,
        (long)N_ * F_, (long)D_ * F_, (long)D_, (long)N_ * D_,
        nullptr, nullptr, nullptr, nullptr, nullptr, nullptr,
        mkSP(9, SB_GEMM));

    // 5) logits = relu(feats @ att_W1^T + att_b1) . W2 + b2  (pinned, fused)
    k_mfma_nt<true, true, false, true>
        <<<SB_GEMM + (A_ / 128) * (N_ / 128) * G_, 256, 0, stream>>>(
        feats, attWb, att_b1, nullptr,
        A_ / 128, N_ / 128, G_, A_, D_,
        (long)N_ * D_, 0L, 0L, 0L,
        att_W2, att_b2, logit, nullptr, nullptr, nullptr,
        mkSP(10, SB_GEMM));

    // 6) out2 = relu(feats[0] @ res_W^T + res_b + sum_g w_g feats_g)
    k_mfma_nt<false, false, true, false>
        <<<SB_GEMM + (D_ / 128) * (N_ / 128) * 1, 256, 0, stream>>>(
        feats, resWb, res_b, nullptr,
        D_ / 128, N_ / 128, 1, D_, D_,
        0L, 0L, 0L, 0L,
        nullptr, nullptr, nullptr, logit, feats, out2,
        mkSP(11, SB_GEMM));

    // 7) remaining streaming at full grid
    k_tail<<<TAILB, 256, 0, stream>>>(tail);
}